// Round 1
// baseline (86.047 us; speedup 1.0000x reference)
//
#include <hip/hip_runtime.h>
#include <math.h>

namespace {

constexpr int Bg   = 2048;   // graphs
constexpr int Nn   = 256;    // nodes per graph
constexpr int Dd   = 128;    // node embed dim
constexpr int Hh   = 4;      // heads
constexpr int SUBn = 32;     // nodes per subset
constexpr int DHd  = 128;    // head embed dim
constexpr int D3   = 384;    // 3*D
constexpr int DH2  = 256;    // 2*DH
constexpr int Gg   = 16;     // graphs per workgroup
constexpr float EPSf = 1e-5f;

__global__ __launch_bounds__(256, 2)
void fused_mhe(const float* __restrict__ emb,
               const float* __restrict__ w1,
               const float* __restrict__ b1,
               const float* __restrict__ g1,
               const float* __restrict__ be1,
               const float* __restrict__ w2,
               const float* __restrict__ b2,
               const float* __restrict__ g2,
               const float* __restrict__ be2,
               const int* __restrict__ subset,
               const int* __restrict__ batch,
               float* __restrict__ out)
{
    __shared__ __align__(16) float comb[D3][Gg];   // 24 KB, [i][g]
    __shared__ __align__(16) float h1s[DH2][Gg];   // 16 KB, [i][g]
    __shared__ int offs[Gg];
    __shared__ int snode[SUBn];

    const int t    = (int)threadIdx.x;
    const int lane = t & 63;
    const int wave = t >> 6;

    const int head  = (int)blockIdx.x / (Bg / Gg);
    const int gblk  = (int)blockIdx.x % (Bg / Gg);
    const int gbase = gblk * Gg;

    // subset node ids for this head
    if (t < SUBn) snode[t] = subset[head * SUBn + t];
    // per-graph offsets: first index in sorted `batch` with value >= graph id
    if (t >= 64 && t < 64 + Gg) {
        const int target = gbase + (t - 64);
        int lo = 0, hi = Bg * Nn;
        while (lo < hi) {
            const int mid = (lo + hi) >> 1;
            if (batch[mid] < target) lo = mid + 1; else hi = mid;
        }
        offs[t - 64] = lo;
    }
    __syncthreads();

    // ---------- Phase A: gather + segment mean/max/sum ----------
    {
        const int d4 = t & 31;   // float4 chunk of D
        const int gl = t >> 5;   // 0..7
        #pragma unroll
        for (int gg = 0; gg < 2; ++gg) {
            const int g = gl + gg * 8;
            const size_t off = (size_t)offs[g];
            float sx = 0.f, sy = 0.f, sz = 0.f, sw = 0.f;
            float mxx = -INFINITY, mxy = -INFINITY, mxz = -INFINITY, mxw = -INFINITY;
            #pragma unroll 8
            for (int s = 0; s < SUBn; ++s) {
                const float4 v = *reinterpret_cast<const float4*>(
                    emb + (off + (size_t)snode[s]) * Dd + d4 * 4);
                sx += v.x; sy += v.y; sz += v.z; sw += v.w;
                mxx = fmaxf(mxx, v.x); mxy = fmaxf(mxy, v.y);
                mxz = fmaxf(mxz, v.z); mxw = fmaxf(mxw, v.w);
            }
            const int d = d4 * 4;
            // mean | max | sum   (1/32 exact)
            comb[d + 0][g] = sx * 0.03125f;
            comb[d + 1][g] = sy * 0.03125f;
            comb[d + 2][g] = sz * 0.03125f;
            comb[d + 3][g] = sw * 0.03125f;
            comb[Dd + d + 0][g] = mxx;
            comb[Dd + d + 1][g] = mxy;
            comb[Dd + d + 2][g] = mxz;
            comb[Dd + d + 3][g] = mxw;
            comb[2 * Dd + d + 0][g] = sx;
            comb[2 * Dd + d + 1][g] = sy;
            comb[2 * Dd + d + 2][g] = sz;
            comb[2 * Dd + d + 3][g] = sw;
        }
    }
    __syncthreads();

    const int g0 = wave * 4;    // each wave owns 4 graphs

    // ---------- Phase B: proj1 (384 x 256) + LN + ReLU ----------
    float harr[4][4];           // [jj][gg]
    {
        const int j0 = lane * 4;
        const float* w1h = w1 + (size_t)head * D3 * DH2;

        const float4 bv = *reinterpret_cast<const float4*>(b1 + head * DH2 + j0);
        float bj[4] = {bv.x, bv.y, bv.z, bv.w};
        float acc[4][4];
        #pragma unroll
        for (int jj = 0; jj < 4; ++jj)
            #pragma unroll
            for (int gg = 0; gg < 4; ++gg)
                acc[jj][gg] = bj[jj];

        #pragma unroll 4
        for (int i = 0; i < D3; ++i) {
            const float4 c4 = *reinterpret_cast<const float4*>(&comb[i][g0]);
            const float4 w4 = *reinterpret_cast<const float4*>(w1h + (size_t)i * DH2 + j0);
            const float cg[4] = {c4.x, c4.y, c4.z, c4.w};
            const float wj[4] = {w4.x, w4.y, w4.z, w4.w};
            #pragma unroll
            for (int jj = 0; jj < 4; ++jj)
                #pragma unroll
                for (int gg = 0; gg < 4; ++gg)
                    acc[jj][gg] = fmaf(wj[jj], cg[gg], acc[jj][gg]);
        }

        const float4 gv  = *reinterpret_cast<const float4*>(g1 + j0);
        const float4 bev = *reinterpret_cast<const float4*>(be1 + j0);
        const float gj[4]  = {gv.x, gv.y, gv.z, gv.w};
        const float bej[4] = {bev.x, bev.y, bev.z, bev.w};

        #pragma unroll
        for (int gg = 0; gg < 4; ++gg) {
            float s1 = acc[0][gg] + acc[1][gg] + acc[2][gg] + acc[3][gg];
            float s2 = acc[0][gg] * acc[0][gg] + acc[1][gg] * acc[1][gg]
                     + acc[2][gg] * acc[2][gg] + acc[3][gg] * acc[3][gg];
            #pragma unroll
            for (int m = 1; m < 64; m <<= 1) {
                s1 += __shfl_xor(s1, m, 64);
                s2 += __shfl_xor(s2, m, 64);
            }
            const float mean = s1 * (1.f / 256.f);
            const float var  = s2 * (1.f / 256.f) - mean * mean;
            const float rstd = rsqrtf(var + EPSf);
            #pragma unroll
            for (int jj = 0; jj < 4; ++jj)
                harr[jj][gg] = fmaxf(0.f, (acc[jj][gg] - mean) * rstd * gj[jj] + bej[jj]);
        }

        // stash h1 (wave-private columns; no barrier needed)
        #pragma unroll
        for (int jj = 0; jj < 4; ++jj)
            *reinterpret_cast<float4*>(&h1s[j0 + jj][g0]) =
                make_float4(harr[jj][0], harr[jj][1], harr[jj][2], harr[jj][3]);
    }

    // ---------- Phase C: proj2 (256 x 128) + LN + ReLU ----------
    {
        const int j0 = lane * 2;
        const float* w2h = w2 + (size_t)head * DH2 * DHd;

        const float2 bv = *reinterpret_cast<const float2*>(b2 + head * DHd + j0);
        float acc[2][4];
        #pragma unroll
        for (int gg = 0; gg < 4; ++gg) { acc[0][gg] = bv.x; acc[1][gg] = bv.y; }

        #pragma unroll 4
        for (int i = 0; i < DH2; ++i) {
            const float4 c4 = *reinterpret_cast<const float4*>(&h1s[i][g0]);
            const float2 w2v = *reinterpret_cast<const float2*>(w2h + (size_t)i * DHd + j0);
            const float cg[4] = {c4.x, c4.y, c4.z, c4.w};
            #pragma unroll
            for (int gg = 0; gg < 4; ++gg) {
                acc[0][gg] = fmaf(w2v.x, cg[gg], acc[0][gg]);
                acc[1][gg] = fmaf(w2v.y, cg[gg], acc[1][gg]);
            }
        }

        const float2 gv  = *reinterpret_cast<const float2*>(g2 + j0);
        const float2 bev = *reinterpret_cast<const float2*>(be2 + j0);

        #pragma unroll
        for (int gg = 0; gg < 4; ++gg) {
            float s1 = acc[0][gg] + acc[1][gg];
            float s2 = acc[0][gg] * acc[0][gg] + acc[1][gg] * acc[1][gg];
            #pragma unroll
            for (int m = 1; m < 64; m <<= 1) {
                s1 += __shfl_xor(s1, m, 64);
                s2 += __shfl_xor(s2, m, 64);
            }
            const float mean = s1 * (1.f / 128.f);
            const float var  = s2 * (1.f / 128.f) - mean * mean;
            const float rstd = rsqrtf(var + EPSf);
            const float o0 = fmaxf(0.f, (acc[0][gg] - mean) * rstd * gv.x + bev.x);
            const float o1 = fmaxf(0.f, (acc[1][gg] - mean) * rstd * gv.y + bev.y);
            const int b = gbase + g0 + gg;
            *reinterpret_cast<float2*>(out + (size_t)b * (Hh * DHd) + head * DHd + j0) =
                make_float2(o0, o1);
        }
    }
}

} // namespace

extern "C" void kernel_launch(void* const* d_in, const int* in_sizes, int n_in,
                              void* d_out, int out_size, void* d_ws, size_t ws_size,
                              hipStream_t stream) {
    const float* emb  = (const float*)d_in[0];
    const float* w1   = (const float*)d_in[1];
    const float* b1   = (const float*)d_in[2];
    const float* g1   = (const float*)d_in[3];
    const float* be1  = (const float*)d_in[4];
    const float* w2   = (const float*)d_in[5];
    const float* b2   = (const float*)d_in[6];
    const float* g2   = (const float*)d_in[7];
    const float* be2  = (const float*)d_in[8];
    const int* subset = (const int*)d_in[9];
    // d_in[10] = head_batch (layout implied by subset indexing, unused)
    const int* batch  = (const int*)d_in[11];
    float* out = (float*)d_out;

    dim3 grid(Hh * (Bg / Gg));   // 512 blocks
    dim3 block(256);
    fused_mhe<<<grid, block, 0, stream>>>(emb, w1, b1, g1, be1,
                                          w2, b2, g2, be2,
                                          subset, batch, out);
}